// Round 15
// baseline (154.159 us; speedup 1.0000x reference)
//
#include <hip/hip_runtime.h>
#include <hip/hip_bf16.h>

#define BB 64
#define TT 1024
#define NN 512
#define LISTCAP (1u << 18)

static constexpr float THR = 0.15f;
static constexpr float SQ    = 6.0f / 127.0f;   // fixed quant scale (±6 sigma range)
static constexpr float INVSQ = 127.0f / 6.0f;

typedef __attribute__((ext_vector_type(4))) int i32x4;

// async global->LDS, 16B per lane; dest = wave-uniform base + lane*16 (HW rule)
__device__ __forceinline__ void gload16(const void* g, void* lds_dst) {
    __builtin_amdgcn_global_load_lds(
        (const __attribute__((address_space(1))) unsigned int*)g,
        (__attribute__((address_space(3))) unsigned int*)lds_dst, 16, 0, 0);
}

// ---------------- kernel T: r6-VERBATIM colsum + fp32->bf16 transpose ----------
// (the proven-fast kernel from r6/r8/r9; untouched logic). Produces xbf[b][col][t]
// bf16 RTZ (t contiguous), s1, dv, nv=||x||, nl=||x - bf16(x)||. Zeroes fired/cnt.
__global__ __launch_bounds__(512) void transpose_colsum(
    const float* __restrict__ x, ushort* __restrict__ xbf,
    float* __restrict__ s1, float* __restrict__ dv,
    float* __restrict__ nv, float* __restrict__ nl,
    unsigned* __restrict__ fired, unsigned* __restrict__ cnt) {
    __shared__ ushort tile[64 * 512];       // 64 KiB
    __shared__ float red[3][8][64];         // 6 KiB
    int b = blockIdx.x, ng = blockIdx.y;
    int n0 = ng * 64;
    int tid = threadIdx.x, w = tid >> 6, l = tid & 63;
    const float* xb = x + (size_t)b * TT * NN;
    float a1 = 0.f, a2 = 0.f, al = 0.f;
    unsigned swz = ((unsigned)l & 7u) << 4;

    if (b == 0 && ng == 0 && tid == 64) *cnt = 0;

    for (int tc = 0; tc < 2; ++tc) {
        for (int i = 0; i < 8; ++i) {
            int tl0 = i * 64 + w * 8;
            int t0 = tc * 512 + tl0;
            unsigned hp[4];
            #pragma unroll
            for (int q = 0; q < 4; ++q) {
                float v0 = xb[(size_t)(t0 + 2 * q) * NN + n0 + l];
                float v1 = xb[(size_t)(t0 + 2 * q + 1) * NN + n0 + l];
                a1 += v0 + v1;
                a2 += v0 * v0 + v1 * v1;
                unsigned u0 = __float_as_uint(v0), u1 = __float_as_uint(v1);
                float h0 = __uint_as_float(u0 & 0xFFFF0000u);
                float h1 = __uint_as_float(u1 & 0xFFFF0000u);
                float l0 = v0 - h0, l1 = v1 - h1;   // exact residuals
                al += l0 * l0 + l1 * l1;
                hp[q] = (u0 >> 16) | (u1 & 0xFFFF0000u);
            }
            unsigned off = (unsigned)l * 1024u + (((unsigned)tl0 * 2u) ^ swz);
            *(uint4*)((char*)tile + off) = make_uint4(hp[0], hp[1], hp[2], hp[3]);
        }
        __syncthreads();
        #pragma unroll
        for (int cc = 0; cc < 8; ++cc) {
            int cl = w * 8 + cc;
            unsigned src = (unsigned)cl * 1024u
                           + (((unsigned)l * 16u) ^ (((unsigned)cl & 7u) << 4));
            uint4 val = *(const uint4*)((char*)tile + src);
            ushort* dst = xbf + ((size_t)(b * NN + n0 + cl) * TT + tc * 512 + l * 8);
            *(uint4*)dst = val;
        }
        __syncthreads();
    }
    red[0][w][l] = a1; red[1][w][l] = a2; red[2][w][l] = al;
    __syncthreads();
    if (tid < 64) {
        float r1 = 0.f, r2 = 0.f, rl = 0.f;
        #pragma unroll
        for (int k = 0; k < 8; ++k) {
            r1 += red[0][k][tid]; r2 += red[1][k][tid]; rl += red[2][k][tid];
        }
        size_t o = (size_t)b * NN + n0 + tid;
        s1[o] = r1;
        dv[o] = r2 - r1 * r1 * (1.0f / TT);
        nv[o] = sqrtf(r2);
        nl[o] = sqrtf(rl);                  // bf16-residual norm (quant8 adds its part)
        fired[o] = 0u;
    }
}

// ---------------- kernel Q: ISOLATED bf16 -> int8 page quantizer ----------------
// Block (b,g) of 512 = 64x8; 512 thr = 8 waves; wave w emits pages s = w, w+8.
// Page (b,g,s) 4 KiB: byte(c',k') = c'*64 + (((k'>>4)^((c'>>1)&3))&3)*16 + (k'&15).
// Lane l: c0 = l>>2, sl = l&3, kk = sl ^ ((c0>>1)&3). For chunk i2 (c' = c0+16*i2;
// note (c'>>1)&3 is i2-invariant), lane reads xbf col (g*64+c') t=[64s+16kk,+16)
// -- 2x contiguous bf16x8, 4 lanes cover a full 64B line -- quantizes 16 elems,
// and the swizzle algebra collapses: kk^((c'>>1)&3) = sl, so the 16 output bytes
// land at page offset 16l + 1024*i2 => CONTIGUOUS 1 KB global writes per instr.
// No LDS on the data path. Accumulates ||bf16 - SQ*q||^2 per column; nl += sqrt
// (triangle inequality keeps the Cauchy-Schwarz bound sound).
__global__ __launch_bounds__(512) void quant8(
    const ushort* __restrict__ xbf, char* __restrict__ xq, float* __restrict__ nl) {
    __shared__ float red[8][64];
    int id = blockIdx.x;
    int b = id >> 3, g = id & 7;
    int tid = threadIdx.x, w = tid >> 6, l = tid & 63;
    int c0 = l >> 2, sl = l & 3;
    int kk = sl ^ ((c0 >> 1) & 3);

    float rq2[4] = {0.f, 0.f, 0.f, 0.f};

    #pragma unroll
    for (int si = 0; si < 2; ++si) {
        int s = w + 8 * si;
        char* pbase = xq + ((size_t)((b * 8 + g) * 16) + s) * 4096;
        #pragma unroll
        for (int i2 = 0; i2 < 4; ++i2) {
            int cp = c0 + 16 * i2;
            const ushort* src = xbf + ((size_t)(b * NN + g * 64 + cp) * TT
                                       + s * 64 + kk * 16);
            ushort4 h0 = *(const ushort4*)(src);
            ushort4 h1 = *(const ushort4*)(src + 4);
            ushort4 h2 = *(const ushort4*)(src + 8);
            ushort4 h3 = *(const ushort4*)(src + 12);
            unsigned pw[4];
            float racc = 0.f;
            #pragma unroll
            for (int qd = 0; qd < 4; ++qd) {
                ushort4 hv = (qd == 0) ? h0 : (qd == 1) ? h1 : (qd == 2) ? h2 : h3;
                unsigned pb = 0;
                #pragma unroll
                for (int j = 0; j < 4; ++j) {
                    unsigned us = (j == 0) ? hv.x : (j == 1) ? hv.y
                                  : (j == 2) ? hv.z : hv.w;
                    float v = __uint_as_float(us << 16);
                    int q = __float2int_rn(v * INVSQ);
                    q = q > 127 ? 127 : (q < -127 ? -127 : q);
                    float r = fmaf((float)q, -SQ, v);
                    racc = fmaf(r, r, racc);
                    pb |= ((unsigned)(q & 255)) << (8 * j);
                }
                pw[qd] = pb;
            }
            rq2[i2] += racc;
            *(uint4*)(pbase + i2 * 1024 + l * 16) =
                make_uint4(pw[0], pw[1], pw[2], pw[3]);
        }
    }

    // ---- per-column residual-norm reduction: quad (sl) -> wave-slot -> block ----
    #pragma unroll
    for (int i2 = 0; i2 < 4; ++i2) {
        rq2[i2] += __shfl_xor(rq2[i2], 1, 64);
        rq2[i2] += __shfl_xor(rq2[i2], 2, 64);
    }
    if (sl == 0) {
        #pragma unroll
        for (int i2 = 0; i2 < 4; ++i2)
            red[w][16 * i2 + c0] = rq2[i2];
    }
    __syncthreads();
    if (tid < 64) {
        float t = 0.f;
        #pragma unroll
        for (int k = 0; k < 8; ++k) t += red[k][tid];
        size_t o = (size_t)b * NN + g * 64 + tid;
        nl[o] = nl[o] + sqrtf(t);           // ||x-SQ*q|| <= nl_bf + nl_q
    }
}

// ---------------- kernel B: i8 MFMA SYRK (r12/r14-verified, ~10-12us) ----------
__global__ __launch_bounds__(256, 8) void corr_mfma(
    const char* __restrict__ xq, const float* __restrict__ s1,
    const float* __restrict__ dv, const float* __restrict__ nv,
    const float* __restrict__ nl, unsigned* __restrict__ fired,
    unsigned* __restrict__ cnt, unsigned* __restrict__ list) {
    __shared__ uint4 ldsbuf[1024];          // 16 KiB
    char* base = (char*)ldsbuf;

    int id = blockIdx.x;
    int swz = ((id & 7) * 288) + (id >> 3);   // 2304 = 8*288
    int b = swz / 36;
    int u = swz % 36;
    int ti = 0, rem = u;
    while (rem >= (8 - ti)) { rem -= (8 - ti); ++ti; }
    int tj = ti + rem;
    int i0 = ti * 64, j0 = tj * 64;
    bool diag = (ti == tj);

    int tid = threadIdx.x;
    int wave = tid >> 6, lane = tid & 63;
    int rl = lane & 15, kg = lane >> 4;

    const char* srcA = xq + ((size_t)(b * 8 + ti) * 16) * 4096 + tid * 16;
    const char* srcB = xq + ((size_t)(b * 8 + tj) * 16) * 4096 + tid * 16;

    auto STAGE = [&](int s, int buf) {
        char* d = base + (buf << 13) + wave * 1024;
        gload16(srcA + (size_t)s * 4096, d);
        if (!diag) gload16(srcB + (size_t)s * 4096, d + 4096);
    };

    int wr = wave >> 1, wc = wave & 1;
    bool skip_mm = diag && (wr == 1) && (wc == 0);

    unsigned aoff[2], boff[2];
    #pragma unroll
    for (int f = 0; f < 2; ++f) {
        unsigned ca = (unsigned)(32 * wr + 16 * f + rl);
        aoff[f] = ca * 64u + ((((unsigned)kg ^ ((ca >> 1) & 3u)) & 3u) << 4);
        unsigned cb2 = (unsigned)(32 * wc + 16 * f + rl);
        boff[f] = cb2 * 64u + ((((unsigned)kg ^ ((cb2 >> 1) & 3u)) & 3u) << 4);
    }
    unsigned bbase = diag ? 0u : 4096u;

    i32x4 acc[2][2];
    #pragma unroll
    for (int i = 0; i < 2; ++i)
        #pragma unroll
        for (int j = 0; j < 2; ++j)
            acc[i][j] = (i32x4)0;

    STAGE(0, 0);
    __syncthreads();

    for (int it = 0; it < 16; ++it) {
        if (it + 1 < 16) STAGE(it + 1, (it + 1) & 1);
        const char* cb = base + ((it & 1) << 13);
        if (!skip_mm) {
            i32x4 A[2], Bv[2];
            #pragma unroll
            for (int f = 0; f < 2; ++f) A[f] = *(const i32x4*)(cb + aoff[f]);
            #pragma unroll
            for (int f = 0; f < 2; ++f) Bv[f] = *(const i32x4*)(cb + bbase + boff[f]);
            #pragma unroll
            for (int fj = 0; fj < 2; ++fj)
                #pragma unroll
                for (int fi = 0; fi < 2; ++fi)
                    acc[fi][fj] = __builtin_amdgcn_mfma_i32_16x16x64_i8(
                        A[fi], Bv[fj], acc[fi][fj], 0, 0, 0);
        }
        __syncthreads();
    }

    // ---- epilogue ----
    const float thr2 = THR * THR;
    const float invT = 1.0f / TT;
    const float s2 = SQ * SQ;
    const float* s1b = s1 + (size_t)b * NN;
    const float* dvb = dv + (size_t)b * NN;
    const float* nvb = nv + (size_t)b * NN;
    const float* nlb = nl + (size_t)b * NN;
    unsigned* fb = fired + (size_t)b * NN;
    int rowb = i0 + 32 * wr + kg * 4;
    int colb = j0 + 32 * wc + rl;
    #pragma unroll
    for (int fj = 0; fj < 2; ++fj) {
        int gj = colb + 16 * fj;
        float sj = s1b[gj], djv = dvb[gj];
        float nvj = nvb[gj], nlj = nlb[gj];
        #pragma unroll
        for (int fi = 0; fi < 2; ++fi) {
            int gi0 = rowb + 16 * fi;
            #pragma unroll
            for (int r = 0; r < 4; ++r) {
                int gi = gi0 + r;
                if (gj > gi) {
                    float cc = s2 * (float)acc[fi][fj][r] - s1b[gi] * sj * invT;
                    float lim = thr2 * dvb[gi] * djv;
                    float nvi = nvb[gi], nli = nlb[gi];
                    float B = nli * nvj + nlj * nvi + 3.0f * nli * nlj
                              + 1e-3f * nvi * nvj;
                    float a = fabsf(cc);
                    float lo = a - B;
                    if (lo > 0.0f && lo * lo > lim) {
                        atomicOr(&fb[gi], 1u);
                    } else if ((a + B) * (a + B) > lim) {
                        unsigned idx = atomicAdd(cnt, 1u);
                        if (idx < LISTCAP)
                            list[idx] = ((unsigned)b << 18) | ((unsigned)gi << 9)
                                        | (unsigned)gj;
                    }
                }
            }
        }
    }
}

// ---------------- kernel B2: exact recompute of borderline pairs ----------------
__global__ __launch_bounds__(256) void cleanup_pairs(
    const float* __restrict__ x, const float* __restrict__ s1,
    const float* __restrict__ dv, const unsigned* __restrict__ cnt,
    const unsigned* __restrict__ list, unsigned* __restrict__ fired) {
    unsigned n = *cnt;
    if (n > LISTCAP) n = LISTCAP;
    int lane = threadIdx.x & 63;
    int gw = (blockIdx.x * 256 + threadIdx.x) >> 6;
    int nw = (gridDim.x * 256) >> 6;
    for (unsigned p = gw; p < n; p += nw) {
        unsigned e = list[p];
        int b = e >> 18, i = (e >> 9) & 511, j = e & 511;
        const float* xb = x + (size_t)b * TT * NN;
        double s = 0.0;
        for (int t = lane; t < TT; t += 64)
            s += (double)xb[(size_t)t * NN + i] * (double)xb[(size_t)t * NN + j];
        #pragma unroll
        for (int o = 32; o > 0; o >>= 1)
            s += __shfl_xor(s, o, 64);
        if (lane == 0) {
            double cov = s - (double)s1[(size_t)b * NN + i]
                             * (double)s1[(size_t)b * NN + j] / (double)TT;
            double lim = (double)THR * (double)THR
                         * (double)dv[(size_t)b * NN + i]
                         * (double)dv[(size_t)b * NN + j];
            if (cov * cov > lim) atomicOr(&fired[(size_t)b * NN + i], 1u);
        }
    }
}

// ---------------- kernel C: finalize mask ----------------
__global__ __launch_bounds__(512) void finalize_mask(
    const unsigned* __restrict__ fired, float* __restrict__ out) {
    int b = blockIdx.x;
    int n = threadIdx.x;
    unsigned f = fired[(size_t)b * NN + n];
    __shared__ int wsum[8];
    unsigned long long m = __ballot(f != 0u);
    int lane = n & 63;
    int w = n >> 6;
    if (lane == 0) wsum[w] = __popcll(m);
    __syncthreads();
    int cnt = 0;
    #pragma unroll
    for (int i = 0; i < 8; ++i) cnt += wsum[i];
    float val = (cnt == 0) ? 1.0f : ((cnt == 1) ? (f ? 1.0f : 0.0f) : 0.0f);
    out[(size_t)b * NN + n] = val;
}

extern "C" void kernel_launch(void* const* d_in, const int* in_sizes, int n_in,
                              void* d_out, int out_size, void* d_ws, size_t ws_size,
                              hipStream_t stream) {
    const float* x = (const float*)d_in[0];
    float* out = (float*)d_out;

    // ws layout (~98 MB)
    ushort* xbf = (ushort*)d_ws;                         // 64 MB bf16 k-major
    char* xq = (char*)(xbf + (size_t)BB * NN * TT);      // 32 MB i8 pages
    float* s1 = (float*)(xq + (size_t)BB * NN * TT);     // B*N
    float* dv = s1 + (size_t)BB * NN;                    // B*N
    float* nv = dv + (size_t)BB * NN;                    // B*N
    float* nl = nv + (size_t)BB * NN;                    // B*N
    unsigned* fired = (unsigned*)(nl + (size_t)BB * NN); // B*N
    unsigned* cnt   = fired + (size_t)BB * NN;           // 16 (padded)
    unsigned* list  = cnt + 16;                          // LISTCAP

    transpose_colsum<<<dim3(BB, 8), 512, 0, stream>>>(x, xbf, s1, dv, nv, nl,
                                                      fired, cnt);
    quant8<<<dim3(512), 512, 0, stream>>>(xbf, xq, nl);
    corr_mfma<<<dim3(2304), 256, 0, stream>>>(xq, s1, dv, nv, nl, fired, cnt, list);
    cleanup_pairs<<<128, 256, 0, stream>>>(x, s1, dv, cnt, list, fired);
    finalize_mask<<<BB, 512, 0, stream>>>(fired, out);
}